// Round 5
// baseline (275.939 us; speedup 1.0000x reference)
//
#include <hip/hip_runtime.h>

typedef short short8 __attribute__((ext_vector_type(8)));
typedef float f32x4 __attribute__((ext_vector_type(4)));

#define CST 3072  // cat row stride (6*512 channels)

__device__ __forceinline__ float bf2f(short s) {
  unsigned u = ((unsigned)(unsigned short)s) << 16;
  return __builtin_bit_cast(float, u);
}
__device__ __forceinline__ short f2bf(float f) {
  unsigned u = __builtin_bit_cast(unsigned, f);
  u = (u + 0x7FFFu + ((u >> 16) & 1u)) >> 16;
  return (short)u;
}
__device__ __forceinline__ void gl16(const short* g, short* l) {
  __builtin_amdgcn_global_load_lds(
      (const __attribute__((address_space(1))) unsigned*)g,
      (__attribute__((address_space(3))) unsigned*)l, 16, 0, 0);
}

// ---- prep: scale_w -> bf16; w_d reorder (27,512,3,3) -> wdr[di][tap][oc pad32][c]; zero stats.
__global__ void k_prep(const float* __restrict__ sw,
                       const float* __restrict__ w1, const float* __restrict__ w2,
                       const float* __restrict__ w3, const float* __restrict__ w4,
                       const float* __restrict__ w5,
                       short* __restrict__ wbf, short* __restrict__ wdr,
                       float* __restrict__ stats) {
  int idx = blockIdx.x * 256 + threadIdx.x;
  const int NS = 512 * 3072;
  const int NW = 5 * 9 * 32 * 512;
  if (idx < NS) {
    wbf[idx] = f2bf(sw[idx]);
  } else if (idx < NS + NW) {
    int j = idx - NS;
    int c = j & 511;
    int t2 = j >> 9;
    int oc = t2 & 31;
    int t3 = t2 >> 5;
    int tap = t3 % 9;
    int di = t3 / 9;
    float v = 0.f;
    if (oc < 27) {
      const float* wp = (di == 0) ? w1 : (di == 1) ? w2 : (di == 2) ? w3 : (di == 3) ? w4 : w5;
      v = wp[((oc * 512 + c) * 3 + tap / 3) * 3 + tap % 3];
    }
    wdr[j] = f2bf(v);
  } else if (idx < NS + NW + 1024) {
    stats[idx - NS - NW] = 0.f;
  }
}

// ---- NCHW fp32 -> NHWC bf16 into cat channel-block 0 (row stride 3072)
__global__ __launch_bounds__(256) void k_transx(const float* __restrict__ x,
                                                short* __restrict__ cat) {
  __shared__ float tile[64][65];
  int b = blockIdx.x;
  int cblk = b & 7, h = (b >> 3) & 63, n = b >> 9;
  int c0 = cblk * 64;
  int t = threadIdx.x;
  int lw = t & 63, grp = t >> 6;
  const float* xp = x + (((size_t)n * 512 + c0) * 64 + h) * 64;
#pragma unroll
  for (int i = 0; i < 16; ++i) {
    int cl = grp * 16 + i;
    tile[cl][lw] = xp[(size_t)cl * 4096 + lw];
  }
  __syncthreads();
  int cl = t & 63;
  size_t mbase = ((size_t)n * 64 + h) * 64;
#pragma unroll
  for (int i = 0; i < 16; ++i) {
    int w = grp * 16 + i;
    cat[(mbase + w) * CST + c0 + cl] = f2bf(tile[cl][w]);
  }
}

// ---- offset conv + softmax + corner-table build.
// Block = 4 tiles (64 pos) of one dilation, XCD-affine; per-tap B in LDS.
// Emits ctab[pos][9] int4: each dword = row(u16) | bf16(filt*bilinear)<<16.
__global__ __launch_bounds__(256) void k_conv(const short* __restrict__ xsrc,
                                              const short* __restrict__ wdr_all,
                                              int* __restrict__ ctab) {
  __shared__ short Bs[32][516];  // stride 516 shorts -> 2-way bank access (free)
  __shared__ float fo[4][16][33];
  int tid = threadIdx.x;
  int wave = tid >> 6, lane = tid & 63;
  int l15 = lane & 15, quad = lane >> 4;
  int b = blockIdx.x;
  int di = b >> 7;
  int loc = b & 127;
  int tile = (loc & 7) * 64 + (loc >> 3) * 4 + wave;  // xcd*64 + slab*4 + wave
  const int DIL[5] = {1, 6, 12, 24, 36};
  int d = DIL[di];
  int m = tile * 16 + l15;
  int n = m >> 12, h = (m >> 6) & 63, w = m & 63;
  f32x4 acc0 = {0.f, 0.f, 0.f, 0.f}, acc1 = {0.f, 0.f, 0.f, 0.f};
  const short8 z8 = {0, 0, 0, 0, 0, 0, 0, 0};
#pragma unroll 1
  for (int tap = 0; tap < 9; ++tap) {
    __syncthreads();
    const short* src = wdr_all + (size_t)(di * 9 + tap) * 32 * 512;
#pragma unroll
    for (int it = 0; it < 8; ++it) {
      int chunk = it * 256 + tid;
      int oc = chunk >> 6;
      int cc = (chunk & 63) * 8;
      *(short8*)(&Bs[oc][cc]) = *(const short8*)(src + oc * 512 + cc);
    }
    __syncthreads();
    int hh = h + (tap / 3 - 1) * d;
    if ((unsigned)hh >= 64u) continue;  // uniform per wave (h uniform in tile)
    int ww = w + (tap % 3 - 1) * d;
    bool ok = (unsigned)ww < 64u;
    int mrow = (n << 12) + (hh << 6) + (ok ? ww : w);
    const short* arow = xsrc + (size_t)mrow * CST + quad * 8;
#pragma unroll 4
    for (int ks = 0; ks < 16; ++ks) {
      short8 a = *(const short8*)(arow + ks * 32);
      if (!ok) a = z8;
      short8 b0 = *(const short8*)(&Bs[l15][ks * 32 + quad * 8]);
      short8 b1 = *(const short8*)(&Bs[l15 + 16][ks * 32 + quad * 8]);
      acc0 = __builtin_amdgcn_mfma_f32_16x16x32_bf16(a, b0, acc0, 0, 0, 0);
      acc1 = __builtin_amdgcn_mfma_f32_16x16x32_bf16(a, b1, acc1, 0, 0, 0);
    }
  }
#pragma unroll
  for (int r = 0; r < 4; ++r) {
    fo[wave][quad * 4 + r][l15] = acc0[r];
    fo[wave][quad * 4 + r][l15 + 16] = acc1[r];
  }
  __syncthreads();
  if (lane < 16) {
    int p = lane;
    float mx = fo[wave][p][0];
#pragma unroll
    for (int k = 1; k < 9; ++k) mx = fmaxf(mx, fo[wave][p][k]);
    float s = 0.f, e[9];
#pragma unroll
    for (int k = 0; k < 9; ++k) { e[k] = __expf(fo[wave][p][k] - mx); s += e[k]; }
    float inv = 1.f / s;
#pragma unroll
    for (int k = 0; k < 9; ++k) fo[wave][p][k] = e[k] * inv;
  }
  __syncthreads();
  // ---- corner table: 16 pos x 9 taps = 144 tasks over lanes 0..47, 3 rounds
#pragma unroll
  for (int t3 = 0; t3 < 3; ++t3) {
    int task = t3 * 48 + lane;
    if (lane < 48) {
      int p = (task * 57) >> 9;       // task/9 for task<512
      int k = task - p * 9;
      float f = fo[wave][p][k];
      float dy = fo[wave][p][9 + 2 * k];
      float dx = fo[wave][p][10 + 2 * k];
      int mm = tile * 16 + p;
      int hh = (mm >> 6) & 63, ww = mm & 63;
      float ys = (float)(hh + (k / 3 - 1) * d) + dy;
      float xs = (float)(ww + (k % 3 - 1) * d) + dx;
      float y0f = floorf(ys), x0f = floorf(xs);
      float wy1 = ys - y0f, wx1 = xs - x0f;
      float wy0 = 1.f - wy1, wx0 = 1.f - wx1;
      int y0 = (int)y0f, x0 = (int)x0f;
      int4 ent;
      int* ep = (int*)&ent;
#pragma unroll
      for (int cy = 0; cy < 2; ++cy)
#pragma unroll
        for (int cx = 0; cx < 2; ++cx) {
          int yy = y0 + cy, xx = x0 + cx;
          bool v = ((unsigned)yy < 64u) && ((unsigned)xx < 64u);
          float wt = f * (cy ? wy1 : wy0) * (cx ? wx1 : wx0);
          int row = v ? (yy * 64 + xx) : 0;
          unsigned wb = v ? (unsigned)(unsigned short)f2bf(wt) : 0u;
          ep[cy * 2 + cx] = row | (int)(wb << 16);
        }
      ((int4*)ctab)[((size_t)di * 8192 + mm) * 9 + k] = ent;
    }
  }
}

// ---- deform bilinear sample from precomputed corner table.
// One position per wave, XCD-affine slab order.
__global__ __launch_bounds__(256, 4) void k_samp(const short* __restrict__ xsrc,
                                                 short* __restrict__ cat,
                                                 const int* __restrict__ ctab) {
  int tid = threadIdx.x;
  int wv = __builtin_amdgcn_readfirstlane(tid >> 6);
  int lane = tid & 63;
  int b = blockIdx.x;
  int di = b >> 11;
  int loc = b & 2047;
  int m = (loc & 7) * 1024 + (loc >> 3) * 4 + wv;  // xcd*1024 + slab*4 + wave
  int n = m >> 12;
  const int4* tp = (const int4*)ctab + ((size_t)di * 8192 + m) * 9;
  const short* xb = xsrc + (size_t)(n << 12) * CST + lane * 8;
  float acc[8] = {0.f, 0.f, 0.f, 0.f, 0.f, 0.f, 0.f, 0.f};
#pragma unroll
  for (int k = 0; k < 9; ++k) {
    int4 e = tp[k];
    const int* ep = (const int*)&e;
#pragma unroll
    for (int c = 0; c < 4; ++c) {
      int dw = ep[c];
      float wt = __builtin_bit_cast(float, (unsigned)dw & 0xFFFF0000u);
      int row = dw & 0xFFFF;
      const short8 vv = *(const short8*)(xb + (size_t)row * CST);
#pragma unroll
      for (int j = 0; j < 8; ++j) acc[j] += wt * bf2f(vv[j]);
    }
  }
  short8 o8;
#pragma unroll
  for (int j = 0; j < 8; ++j) o8[j] = f2bf(acc[j]);
  *(short8*)(cat + (size_t)m * CST + 512 * (di + 1) + lane * 8) = o8;
}

// ---- 1x1 fuse conv: block = 64m x 512n (full N) x half-K; A read ONCE.
// 256 blocks (1/CU), 4 waves, wave tile 64x128 (4x8 frags). B-half (1.5 MB)
// is L2-resident per XCD via kh = xcd&1 affinity. Y halves bf16, summed later.
__global__ __launch_bounds__(256, 1) void k_gemm(const short* __restrict__ A,
                                                 const short* __restrict__ B,
                                                 short* __restrict__ Y) {
  __shared__ short As[64 * 32];    // 4 KB
  __shared__ short Bs[512 * 32];   // 32 KB
  int tid = threadIdx.x;
  int wave = tid >> 6, lane = tid & 63;
  int l15 = lane & 15, quad = lane >> 4;
  int bid = blockIdx.x;            // 0..255
  int xcd = bid & 7;
  int kh = xcd & 1;
  int mt = (bid >> 3) * 4 + (xcd >> 1);  // 0..127
  int m0 = mt * 64;
  int kbeg = kh * 1536;
  int wn = wave * 128;
  f32x4 acc[4][8];
  f32x4 zz = {0.f, 0.f, 0.f, 0.f};
#pragma unroll
  for (int i = 0; i < 4; ++i)
#pragma unroll
    for (int j = 0; j < 8; ++j) acc[i][j] = zz;
  const short* ag = A + (size_t)(m0 + (tid >> 2)) * CST + kbeg + (tid & 3) * 8;
  const short* bg = B + (size_t)(tid >> 2) * CST + kbeg + (tid & 3) * 8;
  short* al = As + tid * 8;
  short* bl = Bs + tid * 8;
#pragma unroll 1
  for (int ks = 0; ks < 48; ++ks) {
    int ko = ks * 32;
    __syncthreads();
    gl16(ag + ko, al);
#pragma unroll
    for (int it = 0; it < 8; ++it)
      gl16(bg + (size_t)it * 64 * CST + ko, bl + it * 2048);
    __syncthreads();
    short8 af[4], bf[8];
#pragma unroll
    for (int i = 0; i < 4; ++i)
      af[i] = *(const short8*)(As + (i * 16 + l15) * 32 + quad * 8);
#pragma unroll
    for (int j = 0; j < 8; ++j)
      bf[j] = *(const short8*)(Bs + (wn + j * 16 + l15) * 32 + quad * 8);
#pragma unroll
    for (int i = 0; i < 4; ++i)
#pragma unroll
      for (int j = 0; j < 8; ++j)
        acc[i][j] = __builtin_amdgcn_mfma_f32_16x16x32_bf16(af[i], bf[j], acc[i][j], 0, 0, 0);
  }
  short* Yp = Y + (size_t)kh * (8192 * 512);
#pragma unroll
  for (int i = 0; i < 4; ++i) {
    int row = m0 + i * 16 + quad * 4;
#pragma unroll
    for (int j = 0; j < 8; ++j) {
      int col = wn + j * 16 + l15;
#pragma unroll
      for (int r = 0; r < 4; ++r)
        Yp[(size_t)(row + r) * 512 + col] = f2bf(acc[i][j][r]);
    }
  }
}

// ---- per-channel sum / sumsq over m of (y0+y1)
__global__ __launch_bounds__(256) void k_stats(const short* __restrict__ Y,
                                               float* __restrict__ stats) {
  const short* Y1 = Y + (size_t)8192 * 512;
  int tid = threadIdx.x;
  int mb = blockIdx.x * 32;
  float s0 = 0.f, q0 = 0.f, s1 = 0.f, q1 = 0.f;
  for (int r = 0; r < 32; ++r) {
    size_t ro = (size_t)(mb + r) * 512;
    float v0 = bf2f(Y[ro + tid]) + bf2f(Y1[ro + tid]);
    float v1 = bf2f(Y[ro + tid + 256]) + bf2f(Y1[ro + tid + 256]);
    s0 += v0; q0 += v0 * v0;
    s1 += v1; q1 += v1 * v1;
  }
  atomicAdd(&stats[tid], s0);
  atomicAdd(&stats[tid + 256], s1);
  atomicAdd(&stats[512 + tid], q0);
  atomicAdd(&stats[512 + tid + 256], q1);
}

// ---- normalize (y0+y1) + NHWC->NCHW transpose -> d_out
__global__ __launch_bounds__(256) void k_norm(const short* __restrict__ Y,
                                              const float* __restrict__ stats,
                                              const float* __restrict__ gamma,
                                              const float* __restrict__ beta,
                                              float* __restrict__ out) {
  __shared__ float tile[64][65];
  const short* Y1 = Y + (size_t)8192 * 512;
  int b = blockIdx.x;
  int cblk = b & 7, h = (b >> 3) & 63, n = b >> 9;
  int c0 = cblk * 64;
  int t = threadIdx.x;
  int cl = t & 63, grp = t >> 6;
  int c = c0 + cl;
  float mean = stats[c] * (1.f / 8192.f);
  float var = stats[512 + c] * (1.f / 8192.f) - mean * mean;
  float Ai = gamma[c] * rsqrtf(var + 1e-5f);
  float Bi = beta[c] - mean * Ai;
  size_t mbase = ((size_t)n * 64 + h) * 64;
#pragma unroll
  for (int i = 0; i < 16; ++i) {
    int w = grp * 16 + i;
    size_t ro = (mbase + w) * 512 + c;
    tile[w][cl] = (bf2f(Y[ro]) + bf2f(Y1[ro])) * Ai + Bi;
  }
  __syncthreads();
  float* op = out + (((size_t)n * 512 + c0) * 64 + h) * 64;
#pragma unroll
  for (int i = 0; i < 16; ++i) {
    int c2 = grp * 16 + i;
    op[(size_t)c2 * 4096 + cl] = tile[cl][c2];
  }
}

extern "C" void kernel_launch(void* const* d_in, const int* in_sizes, int n_in,
                              void* d_out, int out_size, void* d_ws, size_t ws_size,
                              hipStream_t stream) {
  const float* x  = (const float*)d_in[0];
  const float* w1 = (const float*)d_in[1];
  const float* w2 = (const float*)d_in[2];
  const float* w3 = (const float*)d_in[3];
  const float* w4 = (const float*)d_in[4];
  const float* w5 = (const float*)d_in[5];
  const float* sw = (const float*)d_in[6];
  const float* gamma = (const float*)d_in[7];
  const float* beta  = (const float*)d_in[8];
  float* out = (float*)d_out;

  char* ws = (char*)d_ws;
  // workspace layout (bytes):
  // cat   @ 0        : 8192*3072*2    = 50331648   (bf16, block0 = x NHWC)
  // wbf   @ 50331648 : 512*3072*2     = 3145728
  // wdr   @ 53477376 : 5*9*32*512*2   = 1474560
  // yb    @ 54951936 : 2*8192*512*2   = 16777216   (two bf16 K-halves)
  // stats @ 71729152 : 1024*4         = 4096
  // ctab  @ 71733248 : 40960*36*4     = 5898240    (corner table)
  short* cat   = (short*)ws;
  short* wbf   = (short*)(ws + 50331648);
  short* wdr   = (short*)(ws + 53477376);
  short* yb    = (short*)(ws + 54951936);
  float* stats = (float*)(ws + 71729152);
  int*   ctab  = (int*)(ws + 71733248);

  k_prep<<<9028, 256, 0, stream>>>(sw, w1, w2, w3, w4, w5, wbf, wdr, stats);
  k_transx<<<1024, 256, 0, stream>>>(x, cat);
  k_conv<<<640, 256, 0, stream>>>(cat, wdr, ctab);
  k_samp<<<10240, 256, 0, stream>>>(cat, cat, ctab);
  k_gemm<<<256, 256, 0, stream>>>(cat, wbf, yb);
  k_stats<<<256, 256, 0, stream>>>(yb, stats);
  k_norm<<<1024, 256, 0, stream>>>(yb, stats, gamma, beta, out);
}

// Round 6
// 238.565 us; speedup vs baseline: 1.1567x; 1.1567x over previous
//
#include <hip/hip_runtime.h>

typedef short short8 __attribute__((ext_vector_type(8)));
typedef float f32x4 __attribute__((ext_vector_type(4)));

#define CST 3072  // cat row stride (6*512 channels)

__device__ __forceinline__ float bf2f(short s) {
  unsigned u = ((unsigned)(unsigned short)s) << 16;
  return __builtin_bit_cast(float, u);
}
__device__ __forceinline__ short f2bf(float f) {
  unsigned u = __builtin_bit_cast(unsigned, f);
  u = (u + 0x7FFFu + ((u >> 16) & 1u)) >> 16;
  return (short)u;
}
__device__ __forceinline__ void gl16(const short* g, short* l) {
  __builtin_amdgcn_global_load_lds(
      (const __attribute__((address_space(1))) unsigned*)g,
      (__attribute__((address_space(3))) unsigned*)l, 16, 0, 0);
}

// ---- prep: scale_w -> bf16; w_d reorder (27,512,3,3) -> wdr[di][tap][oc pad32][c]; zero stats.
__global__ void k_prep(const float* __restrict__ sw,
                       const float* __restrict__ w1, const float* __restrict__ w2,
                       const float* __restrict__ w3, const float* __restrict__ w4,
                       const float* __restrict__ w5,
                       short* __restrict__ wbf, short* __restrict__ wdr,
                       float* __restrict__ stats) {
  int idx = blockIdx.x * 256 + threadIdx.x;
  const int NS = 512 * 3072;
  const int NW = 5 * 9 * 32 * 512;
  if (idx < NS) {
    wbf[idx] = f2bf(sw[idx]);
  } else if (idx < NS + NW) {
    int j = idx - NS;
    int c = j & 511;
    int t2 = j >> 9;
    int oc = t2 & 31;
    int t3 = t2 >> 5;
    int tap = t3 % 9;
    int di = t3 / 9;
    float v = 0.f;
    if (oc < 27) {
      const float* wp = (di == 0) ? w1 : (di == 1) ? w2 : (di == 2) ? w3 : (di == 3) ? w4 : w5;
      v = wp[((oc * 512 + c) * 3 + tap / 3) * 3 + tap % 3];
    }
    wdr[j] = f2bf(v);
  } else if (idx < NS + NW + 1024) {
    stats[idx - NS - NW] = 0.f;
  }
}

// ---- NCHW fp32 -> NHWC bf16 into cat channel-block 0 (row stride 3072)
__global__ __launch_bounds__(256) void k_transx(const float* __restrict__ x,
                                                short* __restrict__ cat) {
  __shared__ float tile[64][65];
  int b = blockIdx.x;
  int cblk = b & 7, h = (b >> 3) & 63, n = b >> 9;
  int c0 = cblk * 64;
  int t = threadIdx.x;
  int lw = t & 63, grp = t >> 6;
  const float* xp = x + (((size_t)n * 512 + c0) * 64 + h) * 64;
#pragma unroll
  for (int i = 0; i < 16; ++i) {
    int cl = grp * 16 + i;
    tile[cl][lw] = xp[(size_t)cl * 4096 + lw];
  }
  __syncthreads();
  int cl = t & 63;
  size_t mbase = ((size_t)n * 64 + h) * 64;
#pragma unroll
  for (int i = 0; i < 16; ++i) {
    int w = grp * 16 + i;
    cat[(mbase + w) * CST + c0 + cl] = f2bf(tile[cl][w]);
  }
}

// ---- offset conv + softmax + corner-table build.
// Block = 4 tiles (64 pos) of one dilation, XCD-affine; per-tap B in LDS.
// Emits ctab[pos][9] int4: each dword = row(u16) | bf16(filt*bilinear)<<16.
__global__ __launch_bounds__(256) void k_conv(const short* __restrict__ xsrc,
                                              const short* __restrict__ wdr_all,
                                              int* __restrict__ ctab) {
  __shared__ short Bs[32][516];  // stride 516 shorts -> 2-way bank access (free)
  __shared__ float fo[4][16][33];
  int tid = threadIdx.x;
  int wave = tid >> 6, lane = tid & 63;
  int l15 = lane & 15, quad = lane >> 4;
  int b = blockIdx.x;
  int di = b >> 7;
  int loc = b & 127;
  int tile = (loc & 7) * 64 + (loc >> 3) * 4 + wave;  // xcd*64 + slab*4 + wave
  const int DIL[5] = {1, 6, 12, 24, 36};
  int d = DIL[di];
  int m = tile * 16 + l15;
  int n = m >> 12, h = (m >> 6) & 63, w = m & 63;
  f32x4 acc0 = {0.f, 0.f, 0.f, 0.f}, acc1 = {0.f, 0.f, 0.f, 0.f};
  const short8 z8 = {0, 0, 0, 0, 0, 0, 0, 0};
#pragma unroll 1
  for (int tap = 0; tap < 9; ++tap) {
    __syncthreads();
    const short* src = wdr_all + (size_t)(di * 9 + tap) * 32 * 512;
#pragma unroll
    for (int it = 0; it < 8; ++it) {
      int chunk = it * 256 + tid;
      int oc = chunk >> 6;
      int cc = (chunk & 63) * 8;
      *(short8*)(&Bs[oc][cc]) = *(const short8*)(src + oc * 512 + cc);
    }
    __syncthreads();
    int hh = h + (tap / 3 - 1) * d;
    if ((unsigned)hh >= 64u) continue;  // uniform per wave (h uniform in tile)
    int ww = w + (tap % 3 - 1) * d;
    bool ok = (unsigned)ww < 64u;
    int mrow = (n << 12) + (hh << 6) + (ok ? ww : w);
    const short* arow = xsrc + (size_t)mrow * CST + quad * 8;
#pragma unroll 4
    for (int ks = 0; ks < 16; ++ks) {
      short8 a = *(const short8*)(arow + ks * 32);
      if (!ok) a = z8;
      short8 b0 = *(const short8*)(&Bs[l15][ks * 32 + quad * 8]);
      short8 b1 = *(const short8*)(&Bs[l15 + 16][ks * 32 + quad * 8]);
      acc0 = __builtin_amdgcn_mfma_f32_16x16x32_bf16(a, b0, acc0, 0, 0, 0);
      acc1 = __builtin_amdgcn_mfma_f32_16x16x32_bf16(a, b1, acc1, 0, 0, 0);
    }
  }
#pragma unroll
  for (int r = 0; r < 4; ++r) {
    fo[wave][quad * 4 + r][l15] = acc0[r];
    fo[wave][quad * 4 + r][l15 + 16] = acc1[r];
  }
  __syncthreads();
  if (lane < 16) {
    int p = lane;
    float mx = fo[wave][p][0];
#pragma unroll
    for (int k = 1; k < 9; ++k) mx = fmaxf(mx, fo[wave][p][k]);
    float s = 0.f, e[9];
#pragma unroll
    for (int k = 0; k < 9; ++k) { e[k] = __expf(fo[wave][p][k] - mx); s += e[k]; }
    float inv = 1.f / s;
#pragma unroll
    for (int k = 0; k < 9; ++k) fo[wave][p][k] = e[k] * inv;
  }
  __syncthreads();
  // ---- corner table: 16 pos x 9 taps = 144 tasks over lanes 0..47, 3 rounds
#pragma unroll
  for (int t3 = 0; t3 < 3; ++t3) {
    int task = t3 * 48 + lane;
    if (lane < 48) {
      int p = (task * 57) >> 9;       // task/9 for task<512
      int k = task - p * 9;
      float f = fo[wave][p][k];
      float dy = fo[wave][p][9 + 2 * k];
      float dx = fo[wave][p][10 + 2 * k];
      int mm = tile * 16 + p;
      int hh = (mm >> 6) & 63, ww = mm & 63;
      float ys = (float)(hh + (k / 3 - 1) * d) + dy;
      float xs = (float)(ww + (k % 3 - 1) * d) + dx;
      float y0f = floorf(ys), x0f = floorf(xs);
      float wy1 = ys - y0f, wx1 = xs - x0f;
      float wy0 = 1.f - wy1, wx0 = 1.f - wx1;
      int y0 = (int)y0f, x0 = (int)x0f;
      int4 ent;
      int* ep = (int*)&ent;
#pragma unroll
      for (int cy = 0; cy < 2; ++cy)
#pragma unroll
        for (int cx = 0; cx < 2; ++cx) {
          int yy = y0 + cy, xx = x0 + cx;
          bool v = ((unsigned)yy < 64u) && ((unsigned)xx < 64u);
          float wt = f * (cy ? wy1 : wy0) * (cx ? wx1 : wx0);
          int row = v ? (yy * 64 + xx) : 0;
          unsigned wb = v ? (unsigned)(unsigned short)f2bf(wt) : 0u;
          ep[cy * 2 + cx] = row | (int)(wb << 16);
        }
      ((int4*)ctab)[((size_t)di * 8192 + mm) * 9 + k] = ent;
    }
  }
}

// ---- deform bilinear sample from precomputed corner table.
// One position per wave, XCD-affine slab order.
__global__ __launch_bounds__(256, 4) void k_samp(const short* __restrict__ xsrc,
                                                 short* __restrict__ cat,
                                                 const int* __restrict__ ctab) {
  int tid = threadIdx.x;
  int wv = __builtin_amdgcn_readfirstlane(tid >> 6);
  int lane = tid & 63;
  int b = blockIdx.x;
  int di = b >> 11;
  int loc = b & 2047;
  int m = (loc & 7) * 1024 + (loc >> 3) * 4 + wv;  // xcd*1024 + slab*4 + wave
  int n = m >> 12;
  const int4* tp = (const int4*)ctab + ((size_t)di * 8192 + m) * 9;
  const short* xb = xsrc + (size_t)(n << 12) * CST + lane * 8;
  float acc[8] = {0.f, 0.f, 0.f, 0.f, 0.f, 0.f, 0.f, 0.f};
#pragma unroll
  for (int k = 0; k < 9; ++k) {
    int4 e = tp[k];
    const int* ep = (const int*)&e;
#pragma unroll
    for (int c = 0; c < 4; ++c) {
      int dw = ep[c];
      float wt = __builtin_bit_cast(float, (unsigned)dw & 0xFFFF0000u);
      int row = dw & 0xFFFF;
      const short8 vv = *(const short8*)(xb + (size_t)row * CST);
#pragma unroll
      for (int j = 0; j < 8; ++j) acc[j] += wt * bf2f(vv[j]);
    }
  }
  short8 o8;
#pragma unroll
  for (int j = 0; j < 8; ++j) o8[j] = f2bf(acc[j]);
  *(short8*)(cat + (size_t)m * CST + 512 * (di + 1) + lane * 8) = o8;
}

// ---- 1x1 fuse conv: 128x128 tile, half-K per block (kh), BK=64,
// XOR-swizzled LDS (conflict-free ds_read_b128), global_load_lds width 16.
// XCD-affine: 8 blocks sharing an A m-tile land on one XCD (A read once/XCD).
// Y halves bf16, summed in stats/norm.
__global__ __launch_bounds__(256) void k_gemm(const short* __restrict__ A,
                                              const short* __restrict__ B,
                                              short* __restrict__ Y) {
  __shared__ short As[128 * 64];   // 16 KB, swizzled: slot c8' = c8 ^ (row&7)
  __shared__ short Bs[128 * 64];   // 16 KB
  int tid = threadIdx.x;
  int wave = tid >> 6, lane = tid & 63;
  int l15 = lane & 15, quad = lane >> 4;
  int bid = blockIdx.x;            // 0..511
  int xcd = bid & 7, s = bid >> 3;
  int mt = xcd * 8 + (s >> 3);     // same-XCD blocks share A m-tiles
  int nz = s & 7;
  int nt = nz & 3, kh = nz >> 2;
  int m0 = mt * 128, n0 = nt * 128;
  int kbeg = kh * 1536;
  int wm = (wave >> 1) * 64, wn = (wave & 1) * 64;
  f32x4 acc[4][4];
  f32x4 zz = {0.f, 0.f, 0.f, 0.f};
#pragma unroll
  for (int i = 0; i < 4; ++i)
#pragma unroll
    for (int j = 0; j < 4; ++j) acc[i][j] = zz;
  // staging: chunk q = it*256 + tid -> LDS slot q (lane-contiguous),
  // source row = q>>3, col-chunk c8g = (q&7) ^ (row&7)  [swizzle on source]
  const short* agp[4];
  const short* bgp[4];
  short* adst[4];
  short* bdst[4];
#pragma unroll
  for (int it = 0; it < 4; ++it) {
    int q = it * 256 + tid;
    int row = q >> 3;
    int c8g = (q & 7) ^ (row & 7);
    agp[it] = A + (size_t)(m0 + row) * CST + kbeg + c8g * 8;
    bgp[it] = B + (size_t)(n0 + row) * CST + kbeg + c8g * 8;
    adst[it] = As + q * 8;
    bdst[it] = Bs + q * 8;
  }
  int slotbA = (wm + l15) & 7;   // row&7 for this lane's A rows (i*16 doesn't change it)
  int slotbB = (wn + l15) & 7;
#pragma unroll 1
  for (int ks = 0; ks < 24; ++ks) {
    int ko = ks * 64;
    __syncthreads();
#pragma unroll
    for (int it = 0; it < 4; ++it) gl16(agp[it] + ko, adst[it]);
#pragma unroll
    for (int it = 0; it < 4; ++it) gl16(bgp[it] + ko, bdst[it]);
    __syncthreads();
#pragma unroll
    for (int kk = 0; kk < 2; ++kk) {
      int sa = ((quad + kk * 4) ^ slotbA) * 8;
      int sb = ((quad + kk * 4) ^ slotbB) * 8;
      short8 af[4], bf[4];
#pragma unroll
      for (int i = 0; i < 4; ++i)
        af[i] = *(const short8*)(As + (wm + i * 16 + l15) * 64 + sa);
#pragma unroll
      for (int j = 0; j < 4; ++j)
        bf[j] = *(const short8*)(Bs + (wn + j * 16 + l15) * 64 + sb);
#pragma unroll
      for (int i = 0; i < 4; ++i)
#pragma unroll
        for (int j = 0; j < 4; ++j)
          acc[i][j] = __builtin_amdgcn_mfma_f32_16x16x32_bf16(af[i], bf[j], acc[i][j], 0, 0, 0);
    }
  }
  short* Yp = Y + (size_t)kh * (8192 * 512);
#pragma unroll
  for (int i = 0; i < 4; ++i) {
    int row = m0 + wm + i * 16 + quad * 4;
#pragma unroll
    for (int j = 0; j < 4; ++j) {
      int col = n0 + wn + j * 16 + l15;
#pragma unroll
      for (int r = 0; r < 4; ++r)
        Yp[(size_t)(row + r) * 512 + col] = f2bf(acc[i][j][r]);
    }
  }
}

// ---- per-channel sum / sumsq over m of (y0+y1)
__global__ __launch_bounds__(256) void k_stats(const short* __restrict__ Y,
                                               float* __restrict__ stats) {
  const short* Y1 = Y + (size_t)8192 * 512;
  int tid = threadIdx.x;
  int mb = blockIdx.x * 32;
  float s0 = 0.f, q0 = 0.f, s1 = 0.f, q1 = 0.f;
  for (int r = 0; r < 32; ++r) {
    size_t ro = (size_t)(mb + r) * 512;
    float v0 = bf2f(Y[ro + tid]) + bf2f(Y1[ro + tid]);
    float v1 = bf2f(Y[ro + tid + 256]) + bf2f(Y1[ro + tid + 256]);
    s0 += v0; q0 += v0 * v0;
    s1 += v1; q1 += v1 * v1;
  }
  atomicAdd(&stats[tid], s0);
  atomicAdd(&stats[tid + 256], s1);
  atomicAdd(&stats[512 + tid], q0);
  atomicAdd(&stats[512 + tid + 256], q1);
}

// ---- normalize (y0+y1) + NHWC->NCHW transpose -> d_out
__global__ __launch_bounds__(256) void k_norm(const short* __restrict__ Y,
                                              const float* __restrict__ stats,
                                              const float* __restrict__ gamma,
                                              const float* __restrict__ beta,
                                              float* __restrict__ out) {
  __shared__ float tile[64][65];
  const short* Y1 = Y + (size_t)8192 * 512;
  int b = blockIdx.x;
  int cblk = b & 7, h = (b >> 3) & 63, n = b >> 9;
  int c0 = cblk * 64;
  int t = threadIdx.x;
  int cl = t & 63, grp = t >> 6;
  int c = c0 + cl;
  float mean = stats[c] * (1.f / 8192.f);
  float var = stats[512 + c] * (1.f / 8192.f) - mean * mean;
  float Ai = gamma[c] * rsqrtf(var + 1e-5f);
  float Bi = beta[c] - mean * Ai;
  size_t mbase = ((size_t)n * 64 + h) * 64;
#pragma unroll
  for (int i = 0; i < 16; ++i) {
    int w = grp * 16 + i;
    size_t ro = (mbase + w) * 512 + c;
    tile[w][cl] = (bf2f(Y[ro]) + bf2f(Y1[ro])) * Ai + Bi;
  }
  __syncthreads();
  float* op = out + (((size_t)n * 512 + c0) * 64 + h) * 64;
#pragma unroll
  for (int i = 0; i < 16; ++i) {
    int c2 = grp * 16 + i;
    op[(size_t)c2 * 4096 + cl] = tile[cl][c2];
  }
}

extern "C" void kernel_launch(void* const* d_in, const int* in_sizes, int n_in,
                              void* d_out, int out_size, void* d_ws, size_t ws_size,
                              hipStream_t stream) {
  const float* x  = (const float*)d_in[0];
  const float* w1 = (const float*)d_in[1];
  const float* w2 = (const float*)d_in[2];
  const float* w3 = (const float*)d_in[3];
  const float* w4 = (const float*)d_in[4];
  const float* w5 = (const float*)d_in[5];
  const float* sw = (const float*)d_in[6];
  const float* gamma = (const float*)d_in[7];
  const float* beta  = (const float*)d_in[8];
  float* out = (float*)d_out;

  char* ws = (char*)d_ws;
  // workspace layout (bytes):
  // cat   @ 0        : 8192*3072*2    = 50331648   (bf16, block0 = x NHWC)
  // wbf   @ 50331648 : 512*3072*2     = 3145728
  // wdr   @ 53477376 : 5*9*32*512*2   = 1474560
  // yb    @ 54951936 : 2*8192*512*2   = 16777216   (two bf16 K-halves)
  // stats @ 71729152 : 1024*4         = 4096
  // ctab  @ 71733248 : 40960*36*4     = 5898240    (corner table)
  short* cat   = (short*)ws;
  short* wbf   = (short*)(ws + 50331648);
  short* wdr   = (short*)(ws + 53477376);
  short* yb    = (short*)(ws + 54951936);
  float* stats = (float*)(ws + 71729152);
  int*   ctab  = (int*)(ws + 71733248);

  k_prep<<<9028, 256, 0, stream>>>(sw, w1, w2, w3, w4, w5, wbf, wdr, stats);
  k_transx<<<1024, 256, 0, stream>>>(x, cat);
  k_conv<<<640, 256, 0, stream>>>(cat, wdr, ctab);
  k_samp<<<10240, 256, 0, stream>>>(cat, cat, ctab);
  k_gemm<<<512, 256, 0, stream>>>(cat, wbf, yb);
  k_stats<<<256, 256, 0, stream>>>(yb, stats);
  k_norm<<<1024, 256, 0, stream>>>(yb, stats, gamma, beta, out);
}